// Round 7
// baseline (72.785 us; speedup 1.0000x reference)
//
#include <hip/hip_runtime.h>
#include <hip/hip_fp16.h>

// DCNv2: B=2, CIN=COUT=64, H=W=128, DG=8, cpg=8, 3x3 s1 p1 d1
constexpr int BB = 2;
constexpr int CINc = 64;
constexpr int HWc = 128 * 128;
constexpr int OCOFFc = 216;   // DG*3*9 offset-conv channels
constexpr int XP = 130;       // padded spatial dim (halo of 1)

// workspace layout (bytes)
constexpr size_t XT_BYTES  = (size_t)BB * 8 * XP * XP * 8 * 2;   // per-(b,dg) planes, 16B/px
constexpr size_t WB1_OFF   = XT_BYTES;
constexpr size_t WB1_BYTES = (size_t)9 * 256 * 64 * 2;           // offset W [tap][oc256][sl][8] fp16
constexpr size_t WM_OFF    = WB1_OFF + WB1_BYTES;
constexpr size_t WM_BYTES  = (size_t)8 * 12 * 64 * 8 * 2;        // main W [dg][tap12][oc][8c] fp16
constexpr size_t WS_NEEDED = WM_OFF + WM_BYTES;                  // ~4.7 MB

typedef _Float16 f16x8 __attribute__((ext_vector_type(8)));
typedef float    f32x4 __attribute__((ext_vector_type(4)));

// ---------- K0: fused prep: x->planes, weight transforms, halo zero ----------
__global__ void prep_all(const float* __restrict__ x, const float* __restrict__ w_off,
                         const float* __restrict__ weight,
                         __half* __restrict__ xT, __half* __restrict__ wB1,
                         __half* __restrict__ wM) {
    int bid = blockIdx.x;
    if (bid < 1024) {
        int site = bid * 256 + threadIdx.x;      // B*8*HW = 262144
        int pix = site & (HWc - 1);
        int bdg = site >> 14;
        int dg = bdg & 7, b = bdg >> 3;
        int y = pix >> 7, xc = pix & 127;
        const float* xp = x + (size_t)(b * CINc + dg * 8) * HWc + pix;
        __half2 h0 = __halves2half2(__float2half(xp[0 * HWc]), __float2half(xp[1 * HWc]));
        __half2 h1 = __halves2half2(__float2half(xp[2 * HWc]), __float2half(xp[3 * HWc]));
        __half2 h2 = __halves2half2(__float2half(xp[4 * HWc]), __float2half(xp[5 * HWc]));
        __half2 h3 = __halves2half2(__float2half(xp[6 * HWc]), __float2half(xp[7 * HWc]));
        __half2* o = reinterpret_cast<__half2*>(
            xT + (((size_t)(b * 8 + dg) * XP + y + 1) * XP + xc + 1) * 8);
        o[0] = h0; o[1] = h1; o[2] = h2; o[3] = h3;
        return;
    }
    int idx = (bid - 1024) * 256 + threadIdx.x;
    if (idx < 9 * 256 * 64) {
        // wB1[tap][oc][sl][ci], slot sl holds cin-group sl^(oc&7)
        int ci = idx & 7;
        int sl = (idx >> 3) & 7;
        int oc = (idx >> 6) & 255;
        int tap = idx >> 14;
        int cin = ((sl ^ (oc & 7)) << 3) + ci;
        float v = (oc < OCOFFc) ? w_off[oc * 576 + cin * 9 + tap] : 0.f;
        wB1[idx] = __float2half(v);
    } else if (idx < 9 * 256 * 64 + 8 * 12 * 64 * 8) {
        int j = idx - 9 * 256 * 64;          // wM[dg][tap12][oc][c]
        int c = j & 7;
        int oc = (j >> 3) & 63;
        int tg = j >> 9;                      // dg*12 + tap
        int tap = tg % 12;
        int dg = tg / 12;
        float v = (tap < 9) ? weight[oc * 576 + (dg * 8 + c) * 9 + tap] : 0.f;
        wM[j] = __float2half(v);
    } else {
        int j2 = idx - (9 * 256 * 64 + 8 * 12 * 64 * 8);   // halo zero: 16 planes x 516 px
        if (j2 < 16 * 516) {
            int plane = j2 / 516;
            int p = j2 - plane * 516;
            int y, xx;
            if (p < 130)      { y = 0;           xx = p; }
            else if (p < 260) { y = 129;         xx = p - 130; }
            else if (p < 388) { y = 1 + p - 260; xx = 0; }
            else              { y = 1 + p - 388; xx = 129; }
            uint4 z = {0u, 0u, 0u, 0u};
            *reinterpret_cast<uint4*>(xT + (((size_t)plane * XP + y) * XP + xx) * 8) = z;
        }
    }
}

// ---------- Fused DCN: 64px (8x8) tile, 512 thr, 2 blocks/CU ----------
// Phase A: offset conv M=64px x N=256oc x K=576 (waves: 2 px-halves x 4 oc-quarters)
//          -> offsets+masks into LDS (overlaid after Phase A).
// Phase B: wave = (m-frag, oc-half); sampling duplicated across oc-halves;
//          zero barriers in the dg loop.
__global__ __launch_bounds__(512, 4) void dcn_fused_k(
        const __half* __restrict__ xT, const __half* __restrict__ wB1,
        const float* __restrict__ cob, const __half* __restrict__ wM,
        const float* __restrict__ bias, float* __restrict__ out) {
    // LDS plan (bytes): Phase A: xs [0,12800) + wsh0 [12800,45568) + wsh1 [45568,78336)
    //                   Phase B: offsb [0,28512) overlays xs+wsh0 (dead after Phase A)
    __shared__ __align__(16) unsigned char smem[78336];
    __half* xs    = reinterpret_cast<__half*>(smem);           // [row10][col10][sl8][8ch]
    __half* offsb = reinterpret_cast<__half*>(smem);           // [216][66]
    const int tid = threadIdx.x;
    const int bx = blockIdx.x;            // 0..15  (8 px wide)
    const int by = blockIdx.y;            // 0..15  (8 px tall)
    const int b  = blockIdx.z;

    // ---- Phase A staging: x patch rows by*8..+9, cols bx*8..+9, XOR slot swizzle ----
    #pragma unroll
    for (int it = 0; it < 2; ++it) {
        int idx = tid + it * 512;
        if (idx < 800) {
            int yl = idx / 80;                   // 80 = 10 cols * 8 slots
            int rem = idx - yl * 80;
            int cl = rem >> 3, sl = rem & 7;
            int dg = sl ^ (cl & 7);
            float4 v = *reinterpret_cast<const float4*>(
                xT + (((size_t)(b * 8 + dg) * XP + by * 8 + yl) * XP + bx * 8 + cl) * 8);
            *reinterpret_cast<float4*>(xs + idx * 8) = v;
        }
    }
    // W(0) -> regs -> wsh0
    float4 wreg[4];
    #pragma unroll
    for (int i = 0; i < 4; ++i)
        wreg[i] = *reinterpret_cast<const float4*>(wB1 + (size_t)(tid + i * 512) * 8);
    #pragma unroll
    for (int i = 0; i < 4; ++i)
        *reinterpret_cast<float4*>(smem + 12800 + (size_t)(tid + i * 512) * 16) = wreg[i];
    __syncthreads();

    const int lane = tid & 63;
    const int wid = tid >> 6;
    const int l15 = lane & 15, lh = lane >> 4;

    {   // ---- Phase A: 9-tap implicit GEMM, 1 barrier/tap (LDS dbuf weights) ----
        const int wm = wid & 1;            // px half (32 px)
        const int wn = wid >> 1;           // oc quarter (64 oc)
        f32x4 acc[2][4];
        const f32x4 zero = {0.f, 0.f, 0.f, 0.f};
        #pragma unroll
        for (int f = 0; f < 2; ++f)
            #pragma unroll
            for (int ot = 0; ot < 4; ++ot) acc[f][ot] = zero;

        #pragma unroll 1
        for (int tap = 0; tap < 9; ++tap) {
            const int cur = tap & 1;
            __half* wcur = reinterpret_cast<__half*>(smem + 12800 + (cur ? 32768 : 0));
            __half* wnxt = reinterpret_cast<__half*>(smem + 12800 + (cur ? 0 : 32768));
            if (tap < 8) {
                #pragma unroll
                for (int i = 0; i < 4; ++i)
                    wreg[i] = *reinterpret_cast<const float4*>(
                        wB1 + ((size_t)(tap + 1) * 16384 + (tid + i * 512) * 8));
            }
            const int r = tap / 3, s = tap - r * 3;
            const int j = (l15 & 7) + s;              // patch col
            #pragma unroll
            for (int h = 0; h < 2; ++h) {
                const int c = h * 4 + lh;             // cin group 0..7
                const int sl = c ^ (j & 7);
                const int slw = c ^ (l15 & 7);
                f16x8 af[2], bf[4];
                #pragma unroll
                for (int f = 0; f < 2; ++f) {
                    int row = wm * 4 + f * 2 + (l15 >> 3) + r;
                    af[f] = *reinterpret_cast<const f16x8*>(xs + (row * 10 + j) * 64 + sl * 8);
                }
                #pragma unroll
                for (int ot = 0; ot < 4; ++ot) {
                    int oc = wn * 64 + ot * 16 + l15;
                    bf[ot] = *reinterpret_cast<const f16x8*>(wcur + oc * 64 + slw * 8);
                }
                #pragma unroll
                for (int f = 0; f < 2; ++f)
                    #pragma unroll
                    for (int ot = 0; ot < 4; ++ot)
                        acc[f][ot] = __builtin_amdgcn_mfma_f32_16x16x32_f16(
                            af[f], bf[ot], acc[f][ot], 0, 0, 0);
            }
            if (tap < 8) {
                #pragma unroll
                for (int i = 0; i < 4; ++i)
                    *reinterpret_cast<float4*>(
                        reinterpret_cast<unsigned char*>(wnxt) + (size_t)(tid + i * 512) * 16) = wreg[i];
            }
            __syncthreads();   // also guards: after tap 8, xs/wsh reads all done
        }

        // ---- Phase A epilogue -> offsb[oc][px] (overlays xs/wsh0) ----
        #pragma unroll
        for (int ot = 0; ot < 4; ++ot) {
            int oc = wn * 64 + ot * 16 + l15;
            if (oc < OCOFFc) {
                float bi = cob[oc];
                bool sig = (oc >= 144);
                #pragma unroll
                for (int f = 0; f < 2; ++f) {
                    int px = wm * 32 + f * 16 + lh * 4;
                    float v0 = acc[f][ot][0] + bi, v1 = acc[f][ot][1] + bi;
                    float v2 = acc[f][ot][2] + bi, v3 = acc[f][ot][3] + bi;
                    if (sig) {
                        v0 = 1.f / (1.f + __expf(-v0)); v1 = 1.f / (1.f + __expf(-v1));
                        v2 = 1.f / (1.f + __expf(-v2)); v3 = 1.f / (1.f + __expf(-v3));
                    }
                    __half2* d = reinterpret_cast<__half2*>(&offsb[oc * 66 + px]);
                    d[0] = __halves2half2(__float2half(v0), __float2half(v1));
                    d[1] = __halves2half2(__float2half(v2), __float2half(v3));
                }
            }
        }
    }
    __syncthreads();   // offsb complete

    // ---- Phase B: wave = (m-frag, oc-half); no barriers in dg loop ----
    const int m  = wid & 3;            // 16-px m-frag
    const int nh = wid >> 2;           // 32-oc half
    const int px = m * 16 + l15;
    const int gy = by * 8 + (px >> 3), gx = bx * 8 + (px & 7);

    f32x4 acc2[2];
    const f32x4 zero2 = {0.f, 0.f, 0.f, 0.f};
    acc2[0] = zero2; acc2[1] = zero2;

    #pragma unroll 1
    for (int dg = 0; dg < 8; ++dg) {
        // B fragments (3 K-steps x 2 oc-frags); issued before sampling math
        f16x8 bf[6];
        #pragma unroll
        for (int s = 0; s < 3; ++s)
            #pragma unroll
            for (int n = 0; n < 2; ++n)
                bf[s * 2 + n] = *reinterpret_cast<const f16x8*>(
                    wM + (size_t)((dg * 12 + s * 4 + lh) * 64 + nh * 32 + n * 16 + l15) * 8);
        const __half* xb = xT + (size_t)(b * 8 + dg) * XP * XP * 8;

        #pragma unroll
        for (int s = 0; s < 3; ++s) {
            const int kg = s * 4 + lh;        // tap index this lane supplies
            f16x8 af = {0, 0, 0, 0, 0, 0, 0, 0};
            if (kg < 9) {
                float oy = __half2float(offsb[(dg * 18 + kg * 2) * 66 + px]);
                float ox = __half2float(offsb[(dg * 18 + kg * 2 + 1) * 66 + px]);
                float mk = __half2float(offsb[(144 + dg * 9 + kg) * 66 + px]);
                const int ki = kg / 3, kj = kg - ki * 3;
                float sy = oy + (float)(gy - 1 + ki);
                float sx = ox + (float)(gx - 1 + kj);
                float y0f = floorf(sy), x0f = floorf(sx);
                int iy0 = (int)y0f, ix0 = (int)x0f;
                float ly = sy - y0f, lx = sx - x0f;
                float hy = 1.f - ly, hx = 1.f - lx;
                float vy0 = ((unsigned)iy0 < 128u) ? 1.f : 0.f;
                float vy1 = ((unsigned)(iy0 + 1) < 128u) ? 1.f : 0.f;
                float vx0 = ((unsigned)ix0 < 128u) ? 1.f : 0.f;
                float vx1 = ((unsigned)(ix0 + 1) < 128u) ? 1.f : 0.f;
                float w00 = hy * hx * vy0 * vx0 * mk, w01 = hy * lx * vy0 * vx1 * mk;
                float w10 = ly * hx * vy1 * vx0 * mk, w11 = ly * lx * vy1 * vx1 * mk;
                int y0c = min(max(iy0, 0), 127), y1c = min(max(iy0 + 1, 0), 127);
                int x0c = min(max(ix0, 0), 127), x1c = min(max(ix0 + 1, 0), 127);
                float4 f00 = *reinterpret_cast<const float4*>(xb + ((size_t)(y0c + 1) * XP + x0c + 1) * 8);
                float4 f01 = *reinterpret_cast<const float4*>(xb + ((size_t)(y0c + 1) * XP + x1c + 1) * 8);
                float4 f10 = *reinterpret_cast<const float4*>(xb + ((size_t)(y1c + 1) * XP + x0c + 1) * 8);
                float4 f11 = *reinterpret_cast<const float4*>(xb + ((size_t)(y1c + 1) * XP + x1c + 1) * 8);
                const __half2* a00 = reinterpret_cast<const __half2*>(&f00);
                const __half2* a01 = reinterpret_cast<const __half2*>(&f01);
                const __half2* a10 = reinterpret_cast<const __half2*>(&f10);
                const __half2* a11 = reinterpret_cast<const __half2*>(&f11);
                __half2 W00 = __float2half2_rn(w00), W01 = __float2half2_rn(w01);
                __half2 W10 = __float2half2_rn(w10), W11 = __float2half2_rn(w11);
                __align__(16) __half2 rr[4];
                #pragma unroll
                for (int cc = 0; cc < 4; ++cc)
                    rr[cc] = __hfma2(a00[cc], W00,
                             __hfma2(a01[cc], W01,
                             __hfma2(a10[cc], W10, __hmul2(a11[cc], W11))));
                af = *reinterpret_cast<const f16x8*>(rr);
            }
            acc2[0] = __builtin_amdgcn_mfma_f32_16x16x32_f16(af, bf[s * 2 + 0], acc2[0], 0, 0, 0);
            acc2[1] = __builtin_amdgcn_mfma_f32_16x16x32_f16(af, bf[s * 2 + 1], acc2[1], 0, 0, 0);
        }
    }

    // ---- store: D row -> px = m*16 + lh*4 + reg, col -> oc ----
    const int gyo = by * 8 + m * 2 + (lh >> 1);
    const int gx0 = bx * 8 + (lh & 1) * 4;
    #pragma unroll
    for (int n = 0; n < 2; ++n) {
        int oc = nh * 32 + n * 16 + l15;
        float bi = bias[oc];
        float4 v = make_float4(acc2[n][0] + bi, acc2[n][1] + bi,
                               acc2[n][2] + bi, acc2[n][3] + bi);
        *reinterpret_cast<float4*>(
            out + (size_t)(b * 64 + oc) * HWc + gyo * 128 + gx0) = v;
    }
}

extern "C" void kernel_launch(void* const* d_in, const int* in_sizes, int n_in,
                              void* d_out, int out_size, void* d_ws, size_t ws_size,
                              hipStream_t stream) {
    const float* x      = (const float*)d_in[0];
    const float* w_off  = (const float*)d_in[1];
    const float* cob    = (const float*)d_in[2];
    const float* weight = (const float*)d_in[3];
    const float* bias   = (const float*)d_in[4];
    float* out = (float*)d_out;
    if (ws_size < WS_NEEDED) return;

    char* ws = (char*)d_ws;
    __half* xT  = (__half*)ws;
    __half* wB1 = (__half*)(ws + WB1_OFF);
    __half* wM  = (__half*)(ws + WM_OFF);

    prep_all<<<1825, 256, 0, stream>>>(x, w_off, weight, xT, wB1, wM);
    dcn_fused_k<<<dim3(16, 16, 2), 512, 0, stream>>>(xT, wB1, cob, wM, bias, out);
}

// Round 8
// 65.081 us; speedup vs baseline: 1.1184x; 1.1184x over previous
//
#include <hip/hip_runtime.h>
#include <hip/hip_fp16.h>

// DCNv2: B=2, CIN=COUT=64, H=W=128, DG=8, cpg=8, 3x3 s1 p1 d1
constexpr int BB = 2;
constexpr int CINc = 64;
constexpr int HWc = 128 * 128;
constexpr int OCOFFc = 216;   // DG*3*9 offset-conv channels
constexpr int XP = 130;       // padded spatial dim (halo of 1)

// workspace layout (bytes)
constexpr size_t XT_BYTES  = (size_t)BB * 8 * XP * XP * 8 * 2;   // per-(b,dg) planes, 16B/px
constexpr size_t WB1_OFF   = XT_BYTES;
constexpr size_t WB1_BYTES = (size_t)9 * 256 * 64 * 2;           // offset W [tap][oc256][sl][8] fp16
constexpr size_t WM_OFF    = WB1_OFF + WB1_BYTES;
constexpr size_t WM_BYTES  = (size_t)8 * 12 * 64 * 8 * 2;        // main W [dg][tap12][oc][8c] fp16
constexpr size_t WS_NEEDED = WM_OFF + WM_BYTES;                  // ~4.7 MB

typedef _Float16 f16x8 __attribute__((ext_vector_type(8)));
typedef float    f32x4 __attribute__((ext_vector_type(4)));

// ---------- K0: fused prep: x->planes, weight transforms, halo zero ----------
__global__ void prep_all(const float* __restrict__ x, const float* __restrict__ w_off,
                         const float* __restrict__ weight,
                         __half* __restrict__ xT, __half* __restrict__ wB1,
                         __half* __restrict__ wM) {
    int bid = blockIdx.x;
    if (bid < 1024) {
        int site = bid * 256 + threadIdx.x;      // B*8*HW = 262144
        int pix = site & (HWc - 1);
        int bdg = site >> 14;
        int dg = bdg & 7, b = bdg >> 3;
        int y = pix >> 7, xc = pix & 127;
        const float* xp = x + (size_t)(b * CINc + dg * 8) * HWc + pix;
        __half2 h0 = __halves2half2(__float2half(xp[0 * HWc]), __float2half(xp[1 * HWc]));
        __half2 h1 = __halves2half2(__float2half(xp[2 * HWc]), __float2half(xp[3 * HWc]));
        __half2 h2 = __halves2half2(__float2half(xp[4 * HWc]), __float2half(xp[5 * HWc]));
        __half2 h3 = __halves2half2(__float2half(xp[6 * HWc]), __float2half(xp[7 * HWc]));
        __half2* o = reinterpret_cast<__half2*>(
            xT + (((size_t)(b * 8 + dg) * XP + y + 1) * XP + xc + 1) * 8);
        o[0] = h0; o[1] = h1; o[2] = h2; o[3] = h3;
        return;
    }
    int idx = (bid - 1024) * 256 + threadIdx.x;
    if (idx < 9 * 256 * 64) {
        // wB1[tap][oc][sl][ci], slot sl holds cin-group sl^(oc&7)
        int ci = idx & 7;
        int sl = (idx >> 3) & 7;
        int oc = (idx >> 6) & 255;
        int tap = idx >> 14;
        int cin = ((sl ^ (oc & 7)) << 3) + ci;
        float v = (oc < OCOFFc) ? w_off[oc * 576 + cin * 9 + tap] : 0.f;
        wB1[idx] = __float2half(v);
    } else if (idx < 9 * 256 * 64 + 8 * 12 * 64 * 8) {
        int j = idx - 9 * 256 * 64;          // wM[dg][tap12][oc][c]
        int c = j & 7;
        int oc = (j >> 3) & 63;
        int tg = j >> 9;                      // dg*12 + tap
        int tap = tg % 12;
        int dg = tg / 12;
        float v = (tap < 9) ? weight[oc * 576 + (dg * 8 + c) * 9 + tap] : 0.f;
        wM[j] = __float2half(v);
    } else {
        int j2 = idx - (9 * 256 * 64 + 8 * 12 * 64 * 8);   // halo zero: 16 planes x 516 px
        if (j2 < 16 * 516) {
            int plane = j2 / 516;
            int p = j2 - plane * 516;
            int y, xx;
            if (p < 130)      { y = 0;           xx = p; }
            else if (p < 260) { y = 129;         xx = p - 130; }
            else if (p < 388) { y = 1 + p - 260; xx = 0; }
            else              { y = 1 + p - 388; xx = 129; }
            uint4 z = {0u, 0u, 0u, 0u};
            *reinterpret_cast<uint4*>(xT + (((size_t)plane * XP + y) * XP + xx) * 8) = z;
        }
    }
}

// ---------- Fused DCN: 128px (16x8) tile, 1024 thr (16 waves, 4/SIMD), grid 256 ----------
// Phase A: offset conv M=128px x N=256oc x K=576; waves = 4 px-quarters x 4 oc-quarters;
//          dbuf'd weight LDS, 1 barrier/tap; epilogue -> offsb (LDS, overlaid).
// Phase B: wave = (row, dg-half); each wave samples 4 dg (no duplication), zero barriers
//          in dg loop; dg-halves summed via LDS reduction (2 barriers).
__global__ __launch_bounds__(1024, 4) void dcn_fused_k(
        const __half* __restrict__ xT, const __half* __restrict__ wB1,
        const float* __restrict__ cob, const __half* __restrict__ wM,
        const float* __restrict__ bias, float* __restrict__ out) {
    // LDS (bytes): Phase A: xs [0,23040) + wsh0 [23040,55808) + wsh1 [55808,88576)
    //              Phase B: offsb [0,57024) overlays xs+wsh0+head of wsh1 (dead)
    //              Reduce:  redbuf [0,33792) f32 [64 oc][132] overlays dead offsb
    __shared__ __align__(16) unsigned char smem[88576];
    __half* xs    = reinterpret_cast<__half*>(smem);           // [row10][col18][sl8][8ch]
    __half* offsb = reinterpret_cast<__half*>(smem);           // [216][132]
    float*  redbuf = reinterpret_cast<float*>(smem);           // [64][132]
    const int tid = threadIdx.x;
    const int bx = blockIdx.x;            // 0..7   (16 px wide)
    const int by = blockIdx.y;            // 0..15  (8 px tall)
    const int b  = blockIdx.z;

    // ---- Phase A staging: x patch rows by*8..+9, cols bx*16..+17, XOR slot swizzle ----
    #pragma unroll
    for (int it = 0; it < 2; ++it) {
        int idx = tid + it * 1024;
        if (idx < 1440) {
            int yl = idx / 144;                  // 144 = 18 cols * 8 slots
            int rem = idx - yl * 144;
            int cl = rem >> 3, sl = rem & 7;
            int dg = sl ^ (cl & 7);
            float4 v = *reinterpret_cast<const float4*>(
                xT + (((size_t)(b * 8 + dg) * XP + by * 8 + yl) * XP + bx * 16 + cl) * 8);
            *reinterpret_cast<float4*>(xs + idx * 8) = v;
        }
    }
    // W(0) -> regs -> wsh0
    float4 wreg[2];
    #pragma unroll
    for (int i = 0; i < 2; ++i)
        wreg[i] = *reinterpret_cast<const float4*>(wB1 + (size_t)(tid + i * 1024) * 8);
    #pragma unroll
    for (int i = 0; i < 2; ++i)
        *reinterpret_cast<float4*>(smem + 23040 + (size_t)(tid + i * 1024) * 16) = wreg[i];
    __syncthreads();

    const int lane = tid & 63;
    const int wid = tid >> 6;
    const int l15 = lane & 15, lh = lane >> 4;

    {   // ---- Phase A: 9-tap implicit GEMM; wave (wm px-quarter, wn oc-quarter) ----
        const int wm = wid & 3;            // rows wm*2, wm*2+1
        const int wn = wid >> 2;           // oc quarter (64 oc)
        f32x4 acc[2][4];
        const f32x4 zero = {0.f, 0.f, 0.f, 0.f};
        #pragma unroll
        for (int f = 0; f < 2; ++f)
            #pragma unroll
            for (int ot = 0; ot < 4; ++ot) acc[f][ot] = zero;

        #pragma unroll 1
        for (int tap = 0; tap < 9; ++tap) {
            const int cur = tap & 1;
            __half* wcur = reinterpret_cast<__half*>(smem + 23040 + (cur ? 32768 : 0));
            __half* wnxt = reinterpret_cast<__half*>(smem + 23040 + (cur ? 0 : 32768));
            if (tap < 8) {
                #pragma unroll
                for (int i = 0; i < 2; ++i)
                    wreg[i] = *reinterpret_cast<const float4*>(
                        wB1 + ((size_t)(tap + 1) * 16384 + (tid + i * 1024) * 8));
            }
            const int r = tap / 3, s = tap - r * 3;
            const int j = l15 + s;                    // patch col
            #pragma unroll
            for (int h = 0; h < 2; ++h) {
                const int c = h * 4 + lh;             // cin group 0..7
                const int sl = c ^ (j & 7);
                const int slw = c ^ (l15 & 7);
                f16x8 af[2], bf[4];
                #pragma unroll
                for (int f = 0; f < 2; ++f) {
                    int row = wm * 2 + f + r;
                    af[f] = *reinterpret_cast<const f16x8*>(xs + (row * 18 + j) * 64 + sl * 8);
                }
                #pragma unroll
                for (int ot = 0; ot < 4; ++ot) {
                    int oc = wn * 64 + ot * 16 + l15;
                    bf[ot] = *reinterpret_cast<const f16x8*>(wcur + oc * 64 + slw * 8);
                }
                #pragma unroll
                for (int f = 0; f < 2; ++f)
                    #pragma unroll
                    for (int ot = 0; ot < 4; ++ot)
                        acc[f][ot] = __builtin_amdgcn_mfma_f32_16x16x32_f16(
                            af[f], bf[ot], acc[f][ot], 0, 0, 0);
            }
            if (tap < 8) {
                #pragma unroll
                for (int i = 0; i < 2; ++i)
                    *reinterpret_cast<float4*>(
                        reinterpret_cast<unsigned char*>(wnxt) + (size_t)(tid + i * 1024) * 16) = wreg[i];
            }
            __syncthreads();
        }

        // ---- Phase A epilogue -> offsb[r3][px] (overlays dead xs/wsh) ----
        #pragma unroll
        for (int ot = 0; ot < 4; ++ot) {
            int oc = wn * 64 + ot * 16 + l15;
            if (oc < OCOFFc) {
                float bi = cob[oc];
                bool sig = (oc >= 144);
                int dg, k, comp;
                if (oc < 144) { dg = oc / 18; int rem = oc - dg * 18; k = rem >> 1; comp = rem & 1; }
                else          { int mm = oc - 144; dg = mm / 9; k = mm - dg * 9; comp = 2; }
                int r3 = (dg * 9 + k) * 3 + comp;
                #pragma unroll
                for (int f = 0; f < 2; ++f) {
                    int px = (wm * 2 + f) * 16 + lh * 4;
                    float v0 = acc[f][ot][0] + bi, v1 = acc[f][ot][1] + bi;
                    float v2 = acc[f][ot][2] + bi, v3 = acc[f][ot][3] + bi;
                    if (sig) {
                        v0 = 1.f / (1.f + __expf(-v0)); v1 = 1.f / (1.f + __expf(-v1));
                        v2 = 1.f / (1.f + __expf(-v2)); v3 = 1.f / (1.f + __expf(-v3));
                    }
                    __half2* d = reinterpret_cast<__half2*>(&offsb[r3 * 132 + px]);
                    d[0] = __halves2half2(__float2half(v0), __float2half(v1));
                    d[1] = __halves2half2(__float2half(v2), __float2half(v3));
                }
            }
        }
    }
    __syncthreads();   // offsb complete

    // ---- Phase B: wave = (row, dg-half); 4 dg per wave, no barriers in loop ----
    const int row = wid & 7;           // image row within tile
    const int dh  = wid >> 3;          // dg half: 0 -> dg 0..3, 1 -> dg 4..7
    const int px = row * 16 + l15;
    const int gy = by * 8 + row, gx = bx * 16 + l15;

    f32x4 acc2[4];
    const f32x4 zero2 = {0.f, 0.f, 0.f, 0.f};
    #pragma unroll
    for (int n = 0; n < 4; ++n) acc2[n] = zero2;

    #pragma unroll 1
    for (int dgl = 0; dgl < 4; ++dgl) {
        const int dg = dh * 4 + dgl;
        // B fragments (3 K-steps x 4 oc-frags); issued before sampling math
        f16x8 bf[12];
        #pragma unroll
        for (int s = 0; s < 3; ++s)
            #pragma unroll
            for (int n = 0; n < 4; ++n)
                bf[s * 4 + n] = *reinterpret_cast<const f16x8*>(
                    wM + (size_t)((dg * 12 + s * 4 + lh) * 64 + n * 16 + l15) * 8);
        const __half* xb = xT + (size_t)(b * 8 + dg) * XP * XP * 8;

        #pragma unroll
        for (int s = 0; s < 3; ++s) {
            const int kg = s * 4 + lh;        // tap index this lane supplies
            f16x8 af = {0, 0, 0, 0, 0, 0, 0, 0};
            if (kg < 9) {
                const int r3 = (dg * 9 + kg) * 3;
                float oy = __half2float(offsb[r3 * 132 + px]);
                float ox = __half2float(offsb[(r3 + 1) * 132 + px]);
                float mk = __half2float(offsb[(r3 + 2) * 132 + px]);
                const int ki = kg / 3, kj = kg - ki * 3;
                float sy = oy + (float)(gy - 1 + ki);
                float sx = ox + (float)(gx - 1 + kj);
                float y0f = floorf(sy), x0f = floorf(sx);
                int iy0 = (int)y0f, ix0 = (int)x0f;
                float ly = sy - y0f, lx = sx - x0f;
                float hy = 1.f - ly, hx = 1.f - lx;
                float vy0 = ((unsigned)iy0 < 128u) ? 1.f : 0.f;
                float vy1 = ((unsigned)(iy0 + 1) < 128u) ? 1.f : 0.f;
                float vx0 = ((unsigned)ix0 < 128u) ? 1.f : 0.f;
                float vx1 = ((unsigned)(ix0 + 1) < 128u) ? 1.f : 0.f;
                float w00 = hy * hx * vy0 * vx0 * mk, w01 = hy * lx * vy0 * vx1 * mk;
                float w10 = ly * hx * vy1 * vx0 * mk, w11 = ly * lx * vy1 * vx1 * mk;
                int y0c = min(max(iy0, 0), 127), y1c = min(max(iy0 + 1, 0), 127);
                int x0c = min(max(ix0, 0), 127), x1c = min(max(ix0 + 1, 0), 127);
                float4 f00 = *reinterpret_cast<const float4*>(xb + ((size_t)(y0c + 1) * XP + x0c + 1) * 8);
                float4 f01 = *reinterpret_cast<const float4*>(xb + ((size_t)(y0c + 1) * XP + x1c + 1) * 8);
                float4 f10 = *reinterpret_cast<const float4*>(xb + ((size_t)(y1c + 1) * XP + x0c + 1) * 8);
                float4 f11 = *reinterpret_cast<const float4*>(xb + ((size_t)(y1c + 1) * XP + x1c + 1) * 8);
                const __half2* a00 = reinterpret_cast<const __half2*>(&f00);
                const __half2* a01 = reinterpret_cast<const __half2*>(&f01);
                const __half2* a10 = reinterpret_cast<const __half2*>(&f10);
                const __half2* a11 = reinterpret_cast<const __half2*>(&f11);
                __half2 W00 = __float2half2_rn(w00), W01 = __float2half2_rn(w01);
                __half2 W10 = __float2half2_rn(w10), W11 = __float2half2_rn(w11);
                __align__(16) __half2 rr[4];
                #pragma unroll
                for (int cc = 0; cc < 4; ++cc)
                    rr[cc] = __hfma2(a00[cc], W00,
                             __hfma2(a01[cc], W01,
                             __hfma2(a10[cc], W10, __hmul2(a11[cc], W11))));
                af = *reinterpret_cast<const f16x8*>(rr);
            }
            #pragma unroll
            for (int n = 0; n < 4; ++n)
                acc2[n] = __builtin_amdgcn_mfma_f32_16x16x32_f16(af, bf[s * 4 + n], acc2[n], 0, 0, 0);
        }
    }

    __syncthreads();   // all offsb reads done; redbuf may overlay
    // ---- cross-dg-half reduction: dh=1 writes partials, dh=0 adds + stores ----
    if (dh == 1) {
        #pragma unroll
        for (int n = 0; n < 4; ++n) {
            float4 v = make_float4(acc2[n][0], acc2[n][1], acc2[n][2], acc2[n][3]);
            *reinterpret_cast<float4*>(&redbuf[(n * 16 + l15) * 132 + row * 16 + lh * 4]) = v;
        }
    }
    __syncthreads();
    if (dh == 0) {
        #pragma unroll
        for (int n = 0; n < 4; ++n) {
            int oc = n * 16 + l15;
            float4 p = *reinterpret_cast<const float4*>(&redbuf[oc * 132 + row * 16 + lh * 4]);
            float bi = bias[oc];
            float4 v = make_float4(acc2[n][0] + p.x + bi, acc2[n][1] + p.y + bi,
                                   acc2[n][2] + p.z + bi, acc2[n][3] + p.w + bi);
            *reinterpret_cast<float4*>(
                out + (size_t)(b * 64 + oc) * HWc + gy * 128 + bx * 16 + lh * 4) = v;
        }
    }
}

extern "C" void kernel_launch(void* const* d_in, const int* in_sizes, int n_in,
                              void* d_out, int out_size, void* d_ws, size_t ws_size,
                              hipStream_t stream) {
    const float* x      = (const float*)d_in[0];
    const float* w_off  = (const float*)d_in[1];
    const float* cob    = (const float*)d_in[2];
    const float* weight = (const float*)d_in[3];
    const float* bias   = (const float*)d_in[4];
    float* out = (float*)d_out;
    if (ws_size < WS_NEEDED) return;

    char* ws = (char*)d_ws;
    __half* xT  = (__half*)ws;
    __half* wB1 = (__half*)(ws + WB1_OFF);
    __half* wM  = (__half*)(ws + WM_OFF);

    prep_all<<<1825, 256, 0, stream>>>(x, w_off, weight, xT, wB1, wM);
    dcn_fused_k<<<dim3(8, 16, 2), 1024, 0, stream>>>(xT, wB1, cob, wM, bias, out);
}

// Round 9
// 51.444 us; speedup vs baseline: 1.4148x; 1.2651x over previous
//
#include <hip/hip_runtime.h>
#include <hip/hip_fp16.h>

// DCNv2: B=2, CIN=COUT=64, H=W=128, DG=8, cpg=8, 3x3 s1 p1 d1
constexpr int BB = 2;
constexpr int CINc = 64;
constexpr int HWc = 128 * 128;
constexpr int OCOFFc = 216;   // DG*3*9 offset-conv channels
constexpr int XP = 130;       // padded spatial dim (halo of 1)

// workspace layout (bytes)
constexpr size_t XT_BYTES  = (size_t)BB * 8 * XP * XP * 8 * 2;   // per-(b,dg) planes, 16B/px
constexpr size_t WB1_OFF   = XT_BYTES;
constexpr size_t WB1_BYTES = (size_t)9 * 256 * 64 * 2;           // offset W [tap][oc256][sl][8] fp16
constexpr size_t WM_OFF    = WB1_OFF + WB1_BYTES;
constexpr size_t WM_BYTES  = (size_t)8 * 12 * 64 * 8 * 2;        // main W [dg][tap12][oc][8c] fp16
constexpr size_t WS_NEEDED = WM_OFF + WM_BYTES;                  // ~4.7 MB

typedef _Float16 f16x8 __attribute__((ext_vector_type(8)));
typedef float    f32x4 __attribute__((ext_vector_type(4)));

// ---------- K0: fused prep: x->planes, weight transforms, halo zero ----------
__global__ void prep_all(const float* __restrict__ x, const float* __restrict__ w_off,
                         const float* __restrict__ weight,
                         __half* __restrict__ xT, __half* __restrict__ wB1,
                         __half* __restrict__ wM) {
    int bid = blockIdx.x;
    if (bid < 1024) {
        int site = bid * 256 + threadIdx.x;      // B*8*HW = 262144
        int pix = site & (HWc - 1);
        int bdg = site >> 14;
        int dg = bdg & 7, b = bdg >> 3;
        int y = pix >> 7, xc = pix & 127;
        const float* xp = x + (size_t)(b * CINc + dg * 8) * HWc + pix;
        __half2 h0 = __halves2half2(__float2half(xp[0 * HWc]), __float2half(xp[1 * HWc]));
        __half2 h1 = __halves2half2(__float2half(xp[2 * HWc]), __float2half(xp[3 * HWc]));
        __half2 h2 = __halves2half2(__float2half(xp[4 * HWc]), __float2half(xp[5 * HWc]));
        __half2 h3 = __halves2half2(__float2half(xp[6 * HWc]), __float2half(xp[7 * HWc]));
        __half2* o = reinterpret_cast<__half2*>(
            xT + (((size_t)(b * 8 + dg) * XP + y + 1) * XP + xc + 1) * 8);
        o[0] = h0; o[1] = h1; o[2] = h2; o[3] = h3;
        return;
    }
    int idx = (bid - 1024) * 256 + threadIdx.x;
    if (idx < 9 * 256 * 64) {
        // wB1[tap][oc][sl][ci], slot sl holds cin-group sl^(oc&7)
        int ci = idx & 7;
        int sl = (idx >> 3) & 7;
        int oc = (idx >> 6) & 255;
        int tap = idx >> 14;
        int cin = ((sl ^ (oc & 7)) << 3) + ci;
        float v = (oc < OCOFFc) ? w_off[oc * 576 + cin * 9 + tap] : 0.f;
        wB1[idx] = __float2half(v);
    } else if (idx < 9 * 256 * 64 + 8 * 12 * 64 * 8) {
        int j = idx - 9 * 256 * 64;          // wM[dg][tap12][oc][c]
        int c = j & 7;
        int oc = (j >> 3) & 63;
        int tg = j >> 9;                      // dg*12 + tap
        int tap = tg % 12;
        int dg = tg / 12;
        float v = (tap < 9) ? weight[oc * 576 + (dg * 8 + c) * 9 + tap] : 0.f;
        wM[j] = __float2half(v);
    } else {
        int j2 = idx - (9 * 256 * 64 + 8 * 12 * 64 * 8);   // halo zero: 16 planes x 516 px
        if (j2 < 16 * 516) {
            int plane = j2 / 516;
            int p = j2 - plane * 516;
            int y, xx;
            if (p < 130)      { y = 0;           xx = p; }
            else if (p < 260) { y = 129;         xx = p - 130; }
            else if (p < 388) { y = 1 + p - 260; xx = 0; }
            else              { y = 1 + p - 388; xx = 129; }
            uint4 z = {0u, 0u, 0u, 0u};
            *reinterpret_cast<uint4*>(xT + (((size_t)plane * XP + y) * XP + xx) * 8) = z;
        }
    }
}

// Phase B: issue all 12 corner gathers + blend weights for group DG into regs
#define DCN_ISSUE(DG, G, W)                                                    \
  {                                                                            \
    const int dg_ = (DG);                                                      \
    const __half* xb_ = xT + (size_t)(b * 8 + dg_) * XP * XP * 8;              \
    _Pragma("unroll")                                                          \
    for (int s_ = 0; s_ < 3; ++s_) {                                           \
      const int kg_ = s_ * 4 + lh;                                             \
      if (kg_ < 9) {                                                           \
        const int r3_ = (dg_ * 9 + kg_) * 3;                                   \
        float oy_ = __half2float(offsb[r3_ * 132 + px]);                       \
        float ox_ = __half2float(offsb[(r3_ + 1) * 132 + px]);                 \
        float mk_ = __half2float(offsb[(r3_ + 2) * 132 + px]);                 \
        const int ki_ = kg_ / 3, kj_ = kg_ - ki_ * 3;                          \
        float sy_ = oy_ + (float)(gy - 1 + ki_);                               \
        float sx_ = ox_ + (float)(gx - 1 + kj_);                               \
        float y0f_ = floorf(sy_), x0f_ = floorf(sx_);                          \
        int iy0_ = (int)y0f_, ix0_ = (int)x0f_;                                \
        float ly_ = sy_ - y0f_, lx_ = sx_ - x0f_;                              \
        float hy_ = 1.f - ly_, hx_ = 1.f - lx_;                                \
        float vy0_ = ((unsigned)iy0_ < 128u) ? 1.f : 0.f;                      \
        float vy1_ = ((unsigned)(iy0_ + 1) < 128u) ? 1.f : 0.f;                \
        float vx0_ = ((unsigned)ix0_ < 128u) ? 1.f : 0.f;                      \
        float vx1_ = ((unsigned)(ix0_ + 1) < 128u) ? 1.f : 0.f;                \
        W[s_ * 4 + 0] = hy_ * hx_ * vy0_ * vx0_ * mk_;                         \
        W[s_ * 4 + 1] = hy_ * lx_ * vy0_ * vx1_ * mk_;                         \
        W[s_ * 4 + 2] = ly_ * hx_ * vy1_ * vx0_ * mk_;                         \
        W[s_ * 4 + 3] = ly_ * lx_ * vy1_ * vx1_ * mk_;                         \
        int y0c_ = min(max(iy0_, 0), 127), y1c_ = min(max(iy0_ + 1, 0), 127);  \
        int x0c_ = min(max(ix0_, 0), 127), x1c_ = min(max(ix0_ + 1, 0), 127);  \
        G[s_ * 4 + 0] = *reinterpret_cast<const float4*>(xb_ + ((size_t)(y0c_ + 1) * XP + x0c_ + 1) * 8); \
        G[s_ * 4 + 1] = *reinterpret_cast<const float4*>(xb_ + ((size_t)(y0c_ + 1) * XP + x1c_ + 1) * 8); \
        G[s_ * 4 + 2] = *reinterpret_cast<const float4*>(xb_ + ((size_t)(y1c_ + 1) * XP + x0c_ + 1) * 8); \
        G[s_ * 4 + 3] = *reinterpret_cast<const float4*>(xb_ + ((size_t)(y1c_ + 1) * XP + x1c_ + 1) * 8); \
      } else {                                                                 \
        const float4 z4_ = {0.f, 0.f, 0.f, 0.f};                               \
        W[s_ * 4 + 0] = 0.f; W[s_ * 4 + 1] = 0.f;                              \
        W[s_ * 4 + 2] = 0.f; W[s_ * 4 + 3] = 0.f;                              \
        G[s_ * 4 + 0] = z4_; G[s_ * 4 + 1] = z4_;                              \
        G[s_ * 4 + 2] = z4_; G[s_ * 4 + 3] = z4_;                              \
      }                                                                        \
    }                                                                          \
  }

// Phase B: blend staged corners -> af fragments, then 12 MFMAs for group DG
#define DCN_CONSUME(DG, G, W)                                                  \
  {                                                                            \
    const int dg_ = (DG);                                                      \
    f16x8 bf_[12];                                                             \
    _Pragma("unroll")                                                          \
    for (int s_ = 0; s_ < 3; ++s_)                                             \
      _Pragma("unroll")                                                        \
      for (int n_ = 0; n_ < 4; ++n_)                                           \
        bf_[s_ * 4 + n_] = *reinterpret_cast<const f16x8*>(                    \
            wM + (size_t)((dg_ * 12 + s_ * 4 + lh) * 64 + n_ * 16 + l15) * 8); \
    f16x8 af_[3];                                                              \
    _Pragma("unroll")                                                          \
    for (int s_ = 0; s_ < 3; ++s_) {                                           \
      __half2 W00_ = __float2half2_rn(W[s_ * 4 + 0]);                          \
      __half2 W01_ = __float2half2_rn(W[s_ * 4 + 1]);                          \
      __half2 W10_ = __float2half2_rn(W[s_ * 4 + 2]);                          \
      __half2 W11_ = __float2half2_rn(W[s_ * 4 + 3]);                          \
      const __half2* a00_ = reinterpret_cast<const __half2*>(&G[s_ * 4 + 0]);  \
      const __half2* a01_ = reinterpret_cast<const __half2*>(&G[s_ * 4 + 1]);  \
      const __half2* a10_ = reinterpret_cast<const __half2*>(&G[s_ * 4 + 2]);  \
      const __half2* a11_ = reinterpret_cast<const __half2*>(&G[s_ * 4 + 3]);  \
      __align__(16) __half2 rr_[4];                                            \
      _Pragma("unroll")                                                        \
      for (int cc_ = 0; cc_ < 4; ++cc_)                                        \
        rr_[cc_] = __hfma2(a00_[cc_], W00_,                                    \
                   __hfma2(a01_[cc_], W01_,                                    \
                   __hfma2(a10_[cc_], W10_, __hmul2(a11_[cc_], W11_))));       \
      af_[s_] = *reinterpret_cast<const f16x8*>(rr_);                          \
    }                                                                          \
    _Pragma("unroll")                                                          \
    for (int s_ = 0; s_ < 3; ++s_)                                             \
      _Pragma("unroll")                                                        \
      for (int n_ = 0; n_ < 4; ++n_)                                           \
        acc2[n_] = __builtin_amdgcn_mfma_f32_16x16x32_f16(                     \
            af_[s_], bf_[s_ * 4 + n_], acc2[n_], 0, 0, 0);                     \
  }

// ---------- Fused DCN: 128px (16x8) tile, 512 thr (8 waves), grid 256, XCD swizzle ----
// Phase A: offset conv M=128px x N=256oc x K=576 (2 px-halves x 4 oc-quarters),
//          dbuf'd weight LDS, 1 barrier/tap; epilogue -> offsb (LDS).
// Phase B: wave = image row; dg-pipelined register-staged gathers (12 in flight),
//          zero barriers.
__global__ __launch_bounds__(512, 2) void dcn_fused_k(
        const __half* __restrict__ xT, const __half* __restrict__ wB1,
        const float* __restrict__ cob, const __half* __restrict__ wM,
        const float* __restrict__ bias, float* __restrict__ out) {
    __shared__ __half xs[1440 * 8];       // 23040 B: [row10][col18][sl8][8ch]
    __shared__ __half wsh[2][2048 * 8];   // 65536 B: [oc256][sl8][8ch] double-buffered
    __shared__ __half offsb[216 * 132];   // 57024 B: [(dg*9+k)*3+comp][px128 pad132]
    const int tid = threadIdx.x;
    // XCD-aware swizzle: each XCD gets 32 consecutive vids = 4 contiguous row-bands
    const int fid = blockIdx.x + (blockIdx.y << 3) + (blockIdx.z << 7);
    const int vid = ((fid & 7) << 5) + (fid >> 3);
    const int bx = vid & 7;               // 0..7   (16 px wide)
    const int by = (vid >> 3) & 15;       // 0..15  (8 px tall)
    const int b  = vid >> 7;

    // ---- Phase A staging: x patch rows by*8..+9, cols bx*16..+17, XOR slot swizzle ----
    #pragma unroll
    for (int it = 0; it < 3; ++it) {
        int idx = tid + it * 512;
        if (idx < 1440) {
            int yl = idx / 144;                  // 144 = 18 cols * 8 slots
            int rem = idx - yl * 144;
            int cl = rem >> 3, sl = rem & 7;
            int dg = sl ^ (cl & 7);
            float4 v = *reinterpret_cast<const float4*>(
                xT + (((size_t)(b * 8 + dg) * XP + by * 8 + yl) * XP + bx * 16 + cl) * 8);
            *reinterpret_cast<float4*>(xs + idx * 8) = v;
        }
    }
    // W(0) -> regs -> wsh[0]
    float4 wreg[4];
    #pragma unroll
    for (int i = 0; i < 4; ++i)
        wreg[i] = *reinterpret_cast<const float4*>(wB1 + (size_t)(tid + i * 512) * 8);
    #pragma unroll
    for (int i = 0; i < 4; ++i)
        *reinterpret_cast<float4*>(&wsh[0][(tid + i * 512) * 8]) = wreg[i];
    __syncthreads();

    const int lane = tid & 63;
    const int wid = tid >> 6;
    const int l15 = lane & 15, lh = lane >> 4;

    {   // ---- Phase A: 9-tap implicit GEMM, 1 barrier/tap ----
        const int wr = wid & 1;            // px half (4 image rows)
        const int wc = wid >> 1;           // oc quarter (64 of 256)
        f32x4 acc[4][4];
        const f32x4 zero = {0.f, 0.f, 0.f, 0.f};
        #pragma unroll
        for (int ty = 0; ty < 4; ++ty)
            #pragma unroll
            for (int ot = 0; ot < 4; ++ot) acc[ty][ot] = zero;

        #pragma unroll 1
        for (int tap = 0; tap < 9; ++tap) {
            const int cur = tap & 1;
            if (tap < 8) {
                #pragma unroll
                for (int i = 0; i < 4; ++i)
                    wreg[i] = *reinterpret_cast<const float4*>(
                        wB1 + ((size_t)(tap + 1) * 16384 + (tid + i * 512) * 8));
            }
            const int r = tap / 3, s = tap - r * 3;
            const int j = l15 + s;                    // patch col
            #pragma unroll
            for (int h = 0; h < 2; ++h) {
                const int c = h * 4 + lh;             // cin group 0..7
                const int sl = c ^ (j & 7);
                f16x8 af[4], bf[4];
                #pragma unroll
                for (int ty = 0; ty < 4; ++ty) {
                    int row = wr * 4 + ty + r;
                    af[ty] = *reinterpret_cast<const f16x8*>(xs + (row * 18 + j) * 64 + sl * 8);
                }
                #pragma unroll
                for (int ot = 0; ot < 4; ++ot) {
                    int oc = wc * 64 + ot * 16 + l15;
                    int slw = c ^ (oc & 7);
                    bf[ot] = *reinterpret_cast<const f16x8*>(&wsh[cur][oc * 64 + slw * 8]);
                }
                #pragma unroll
                for (int ty = 0; ty < 4; ++ty)
                    #pragma unroll
                    for (int ot = 0; ot < 4; ++ot)
                        acc[ty][ot] = __builtin_amdgcn_mfma_f32_16x16x32_f16(
                            af[ty], bf[ot], acc[ty][ot], 0, 0, 0);
            }
            if (tap < 8) {
                #pragma unroll
                for (int i = 0; i < 4; ++i)
                    *reinterpret_cast<float4*>(&wsh[cur ^ 1][(tid + i * 512) * 8]) = wreg[i];
            }
            __syncthreads();
        }

        // ---- Phase A epilogue -> offsb (LDS). D: oc=l15-col, x-offset=lh*4+reg ----
        #pragma unroll
        for (int ot = 0; ot < 4; ++ot) {
            int oc = wc * 64 + ot * 16 + l15;
            if (oc < OCOFFc) {
                float bi = cob[oc];
                bool sig = (oc >= 144);
                int dg, k, comp;
                if (oc < 144) { dg = oc / 18; int rem = oc - dg * 18; k = rem >> 1; comp = rem & 1; }
                else          { int mm = oc - 144; dg = mm / 9; k = mm - dg * 9; comp = 2; }
                int r3 = (dg * 9 + k) * 3 + comp;
                #pragma unroll
                for (int ty = 0; ty < 4; ++ty) {
                    int px = (wr * 4 + ty) * 16 + lh * 4;
                    float v0 = acc[ty][ot][0] + bi, v1 = acc[ty][ot][1] + bi;
                    float v2 = acc[ty][ot][2] + bi, v3 = acc[ty][ot][3] + bi;
                    if (sig) {
                        v0 = 1.f / (1.f + __expf(-v0)); v1 = 1.f / (1.f + __expf(-v1));
                        v2 = 1.f / (1.f + __expf(-v2)); v3 = 1.f / (1.f + __expf(-v3));
                    }
                    __half2* d = reinterpret_cast<__half2*>(&offsb[r3 * 132 + px]);
                    d[0] = __halves2half2(__float2half(v0), __float2half(v1));
                    d[1] = __halves2half2(__float2half(v2), __float2half(v3));
                }
            }
        }
    }
    __syncthreads();   // offsb complete

    // ---- Phase B: wave = image row; dg-pipelined register-staged sampling ----
    const int px = wid * 16 + l15;    // offsb px index
    const int gy = by * 8 + wid;
    const int gx = bx * 16 + l15;

    f32x4 acc2[4];
    const f32x4 zero2 = {0.f, 0.f, 0.f, 0.f};
    #pragma unroll
    for (int n = 0; n < 4; ++n) acc2[n] = zero2;

    float4 gA[12]; float wA[12];
    float4 gB[12]; float wB[12];

    DCN_ISSUE(0, gA, wA);
    #pragma unroll 1
    for (int d = 0; d < 8; d += 2) {
        DCN_ISSUE(d + 1, gB, wB);
        DCN_CONSUME(d, gA, wA);
        if (d + 2 < 8) DCN_ISSUE(d + 2, gA, wA);
        DCN_CONSUME(d + 1, gB, wB);
    }

    // ---- store: D row -> x-offset (lh*4+reg), col -> oc (n*16+l15) ----
    #pragma unroll
    for (int n = 0; n < 4; ++n) {
        int oc = n * 16 + l15;
        float bi = bias[oc];
        float4 v = make_float4(acc2[n][0] + bi, acc2[n][1] + bi,
                               acc2[n][2] + bi, acc2[n][3] + bi);
        *reinterpret_cast<float4*>(
            out + (size_t)(b * 64 + oc) * HWc + gy * 128 + bx * 16 + lh * 4) = v;
    }
}

extern "C" void kernel_launch(void* const* d_in, const int* in_sizes, int n_in,
                              void* d_out, int out_size, void* d_ws, size_t ws_size,
                              hipStream_t stream) {
    const float* x      = (const float*)d_in[0];
    const float* w_off  = (const float*)d_in[1];
    const float* cob    = (const float*)d_in[2];
    const float* weight = (const float*)d_in[3];
    const float* bias   = (const float*)d_in[4];
    float* out = (float*)d_out;
    if (ws_size < WS_NEEDED) return;

    char* ws = (char*)d_ws;
    __half* xT  = (__half*)ws;
    __half* wB1 = (__half*)(ws + WB1_OFF);
    __half* wM  = (__half*)(ws + WM_OFF);

    prep_all<<<1825, 256, 0, stream>>>(x, w_off, weight, xT, wB1, wM);
    dcn_fused_k<<<dim3(8, 16, 2), 512, 0, stream>>>(xT, wB1, cob, wM, bias, out);
}

// Round 10
// 39.361 us; speedup vs baseline: 1.8492x; 1.3070x over previous
//
#include <hip/hip_runtime.h>
#include <hip/hip_fp16.h>

// DCNv2: B=2, CIN=COUT=64, H=W=128, DG=8, cpg=8, 3x3 s1 p1 d1
constexpr int BB = 2;
constexpr int CINc = 64;
constexpr int HWc = 128 * 128;
constexpr int OCOFFc = 216;   // DG*3*9 offset-conv channels
constexpr int XP = 130;       // padded spatial dim (halo of 1)

// workspace layout (bytes)
constexpr size_t XT_BYTES  = (size_t)BB * 8 * XP * XP * 8 * 2;   // per-(b,dg) planes, 16B/px
constexpr size_t WB1_OFF   = XT_BYTES;
constexpr size_t WB1_BYTES = (size_t)9 * 8 * 256 * 8 * 2;        // offset W [tap][cgrp][oc256][8ci] fp16
constexpr size_t WM_OFF    = WB1_OFF + WB1_BYTES;
constexpr size_t WM_BYTES  = (size_t)8 * 12 * 64 * 8 * 2;        // main W [dg][tap12][oc][8c] fp16
constexpr size_t WS_NEEDED = WM_OFF + WM_BYTES;                  // ~4.7 MB

typedef _Float16 f16x8 __attribute__((ext_vector_type(8)));
typedef float    f32x4 __attribute__((ext_vector_type(4)));

// ---------- K0: fused prep: x->planes, weight transforms, halo zero ----------
__global__ void prep_all(const float* __restrict__ x, const float* __restrict__ w_off,
                         const float* __restrict__ weight,
                         __half* __restrict__ xT, __half* __restrict__ wB1,
                         __half* __restrict__ wM) {
    int bid = blockIdx.x;
    if (bid < 1024) {
        int site = bid * 256 + threadIdx.x;      // B*8*HW = 262144
        int pix = site & (HWc - 1);
        int bdg = site >> 14;
        int dg = bdg & 7, b = bdg >> 3;
        int y = pix >> 7, xc = pix & 127;
        const float* xp = x + (size_t)(b * CINc + dg * 8) * HWc + pix;
        __half2 h0 = __halves2half2(__float2half(xp[0 * HWc]), __float2half(xp[1 * HWc]));
        __half2 h1 = __halves2half2(__float2half(xp[2 * HWc]), __float2half(xp[3 * HWc]));
        __half2 h2 = __halves2half2(__float2half(xp[4 * HWc]), __float2half(xp[5 * HWc]));
        __half2 h3 = __halves2half2(__float2half(xp[6 * HWc]), __float2half(xp[7 * HWc]));
        __half2* o = reinterpret_cast<__half2*>(
            xT + (((size_t)(b * 8 + dg) * XP + y + 1) * XP + xc + 1) * 8);
        o[0] = h0; o[1] = h1; o[2] = h2; o[3] = h3;
        return;
    }
    int idx = (bid - 1024) * 256 + threadIdx.x;
    if (idx < 9 * 8 * 256 * 8) {
        // wB1[tap][cgrp][oc][ci]: fragment-major, coalesced for direct global B-reads
        int ci = idx & 7;
        int oc = (idx >> 3) & 255;
        int c  = (idx >> 11) & 7;
        int tap = idx >> 14;
        float v = (oc < OCOFFc) ? w_off[oc * 576 + (c * 8 + ci) * 9 + tap] : 0.f;
        wB1[idx] = __float2half(v);
    } else if (idx < 9 * 8 * 256 * 8 + 8 * 12 * 64 * 8) {
        int j = idx - 9 * 8 * 256 * 8;       // wM[dg][tap12][oc][c]
        int c = j & 7;
        int oc = (j >> 3) & 63;
        int tg = j >> 9;                      // dg*12 + tap
        int tap = tg % 12;
        int dg = tg / 12;
        float v = (tap < 9) ? weight[oc * 576 + (dg * 8 + c) * 9 + tap] : 0.f;
        wM[j] = __float2half(v);
    } else {
        int j2 = idx - (9 * 8 * 256 * 8 + 8 * 12 * 64 * 8);   // halo zero: 16 planes x 516 px
        if (j2 < 16 * 516) {
            int plane = j2 / 516;
            int p = j2 - plane * 516;
            int y, xx;
            if (p < 130)      { y = 0;           xx = p; }
            else if (p < 260) { y = 129;         xx = p - 130; }
            else if (p < 388) { y = 1 + p - 260; xx = 0; }
            else              { y = 1 + p - 388; xx = 129; }
            uint4 z = {0u, 0u, 0u, 0u};
            *reinterpret_cast<uint4*>(xT + (((size_t)plane * XP + y) * XP + xx) * 8) = z;
        }
    }
}

// Phase B: issue all 12 corner gathers + blend weights for group DG into regs
#define DCN_ISSUE(DG, G, W)                                                    \
  {                                                                            \
    const int dg_ = (DG);                                                      \
    const __half* xb_ = xT + (size_t)(b * 8 + dg_) * XP * XP * 8;              \
    _Pragma("unroll")                                                          \
    for (int s_ = 0; s_ < 3; ++s_) {                                           \
      const int kg_ = s_ * 4 + lh;                                             \
      if (kg_ < 9) {                                                           \
        const int r3_ = (dg_ * 9 + kg_) * 3;                                   \
        float oy_ = __half2float(offsb[r3_ * 132 + px]);                       \
        float ox_ = __half2float(offsb[(r3_ + 1) * 132 + px]);                 \
        float mk_ = __half2float(offsb[(r3_ + 2) * 132 + px]);                 \
        const int ki_ = kg_ / 3, kj_ = kg_ - ki_ * 3;                          \
        float sy_ = oy_ + (float)(gy - 1 + ki_);                               \
        float sx_ = ox_ + (float)(gx - 1 + kj_);                               \
        float y0f_ = floorf(sy_), x0f_ = floorf(sx_);                          \
        int iy0_ = (int)y0f_, ix0_ = (int)x0f_;                                \
        float ly_ = sy_ - y0f_, lx_ = sx_ - x0f_;                              \
        float hy_ = 1.f - ly_, hx_ = 1.f - lx_;                                \
        float vy0_ = ((unsigned)iy0_ < 128u) ? 1.f : 0.f;                      \
        float vy1_ = ((unsigned)(iy0_ + 1) < 128u) ? 1.f : 0.f;                \
        float vx0_ = ((unsigned)ix0_ < 128u) ? 1.f : 0.f;                      \
        float vx1_ = ((unsigned)(ix0_ + 1) < 128u) ? 1.f : 0.f;                \
        W[s_ * 4 + 0] = hy_ * hx_ * vy0_ * vx0_ * mk_;                         \
        W[s_ * 4 + 1] = hy_ * lx_ * vy0_ * vx1_ * mk_;                         \
        W[s_ * 4 + 2] = ly_ * hx_ * vy1_ * vx0_ * mk_;                         \
        W[s_ * 4 + 3] = ly_ * lx_ * vy1_ * vx1_ * mk_;                         \
        int y0c_ = min(max(iy0_, 0), 127), y1c_ = min(max(iy0_ + 1, 0), 127);  \
        int x0c_ = min(max(ix0_, 0), 127), x1c_ = min(max(ix0_ + 1, 0), 127);  \
        G[s_ * 4 + 0] = *reinterpret_cast<const float4*>(xb_ + ((size_t)(y0c_ + 1) * XP + x0c_ + 1) * 8); \
        G[s_ * 4 + 1] = *reinterpret_cast<const float4*>(xb_ + ((size_t)(y0c_ + 1) * XP + x1c_ + 1) * 8); \
        G[s_ * 4 + 2] = *reinterpret_cast<const float4*>(xb_ + ((size_t)(y1c_ + 1) * XP + x0c_ + 1) * 8); \
        G[s_ * 4 + 3] = *reinterpret_cast<const float4*>(xb_ + ((size_t)(y1c_ + 1) * XP + x1c_ + 1) * 8); \
      } else {                                                                 \
        const float4 z4_ = {0.f, 0.f, 0.f, 0.f};                               \
        W[s_ * 4 + 0] = 0.f; W[s_ * 4 + 1] = 0.f;                              \
        W[s_ * 4 + 2] = 0.f; W[s_ * 4 + 3] = 0.f;                              \
        G[s_ * 4 + 0] = z4_; G[s_ * 4 + 1] = z4_;                              \
        G[s_ * 4 + 2] = z4_; G[s_ * 4 + 3] = z4_;                              \
      }                                                                        \
    }                                                                          \
  }

// Phase B: blend staged corners -> af fragments, then 12 MFMAs for group DG
#define DCN_CONSUME(DG, G, W)                                                  \
  {                                                                            \
    const int dg_ = (DG);                                                      \
    f16x8 bf_[12];                                                             \
    _Pragma("unroll")                                                          \
    for (int s_ = 0; s_ < 3; ++s_)                                             \
      _Pragma("unroll")                                                        \
      for (int n_ = 0; n_ < 4; ++n_)                                           \
        bf_[s_ * 4 + n_] = *reinterpret_cast<const f16x8*>(                    \
            wM + (size_t)((dg_ * 12 + s_ * 4 + lh) * 64 + n_ * 16 + l15) * 8); \
    f16x8 af_[3];                                                              \
    _Pragma("unroll")                                                          \
    for (int s_ = 0; s_ < 3; ++s_) {                                           \
      __half2 W00_ = __float2half2_rn(W[s_ * 4 + 0]);                          \
      __half2 W01_ = __float2half2_rn(W[s_ * 4 + 1]);                          \
      __half2 W10_ = __float2half2_rn(W[s_ * 4 + 2]);                          \
      __half2 W11_ = __float2half2_rn(W[s_ * 4 + 3]);                          \
      const __half2* a00_ = reinterpret_cast<const __half2*>(&G[s_ * 4 + 0]);  \
      const __half2* a01_ = reinterpret_cast<const __half2*>(&G[s_ * 4 + 1]);  \
      const __half2* a10_ = reinterpret_cast<const __half2*>(&G[s_ * 4 + 2]);  \
      const __half2* a11_ = reinterpret_cast<const __half2*>(&G[s_ * 4 + 3]);  \
      __align__(16) __half2 rr_[4];                                            \
      _Pragma("unroll")                                                        \
      for (int cc_ = 0; cc_ < 4; ++cc_)                                        \
        rr_[cc_] = __hfma2(a00_[cc_], W00_,                                    \
                   __hfma2(a01_[cc_], W01_,                                    \
                   __hfma2(a10_[cc_], W10_, __hmul2(a11_[cc_], W11_))));       \
      af_[s_] = *reinterpret_cast<const f16x8*>(rr_);                          \
    }                                                                          \
    _Pragma("unroll")                                                          \
    for (int s_ = 0; s_ < 3; ++s_)                                             \
      _Pragma("unroll")                                                        \
      for (int n_ = 0; n_ < 4; ++n_)                                           \
        acc2[n_] = __builtin_amdgcn_mfma_f32_16x16x32_f16(                     \
            af_[s_], bf_[s_ * 4 + n_], acc2[n_], 0, 0, 0);                     \
  }

// ---------- Fused DCN: 128px tile, 512 thr, grid 256, XCD swizzle ----------
// Phase A: offset conv, B-fragments streamed DIRECTLY from global (L2-resident,
//          coalesced) -> no weight LDS, no per-tap barriers. 2 barriers total.
// Phase B: wave = image row; dg-pipelined register-staged gathers.
__global__ __launch_bounds__(512, 2) void dcn_fused_k(
        const __half* __restrict__ xT, const __half* __restrict__ wB1,
        const float* __restrict__ cob, const __half* __restrict__ wM,
        const float* __restrict__ bias, float* __restrict__ out) {
    __shared__ __half xs[1440 * 8];       // 23040 B: [row10][col18][sl8][8ch]
    __shared__ __half offsb[216 * 132];   // 57024 B: [(dg*9+k)*3+comp][px128 pad132]
    const int tid = threadIdx.x;
    // XCD-aware swizzle: each XCD gets 32 consecutive vids = 4 contiguous row-bands
    const int fid = blockIdx.x + (blockIdx.y << 3) + (blockIdx.z << 7);
    const int vid = ((fid & 7) << 5) + (fid >> 3);
    const int bx = vid & 7;               // 0..7   (16 px wide)
    const int by = (vid >> 3) & 15;       // 0..15  (8 px tall)
    const int b  = vid >> 7;

    // ---- Phase A staging: x patch rows by*8..+9, cols bx*16..+17, XOR slot swizzle ----
    #pragma unroll
    for (int it = 0; it < 3; ++it) {
        int idx = tid + it * 512;
        if (idx < 1440) {
            int yl = idx / 144;                  // 144 = 18 cols * 8 slots
            int rem = idx - yl * 144;
            int cl = rem >> 3, sl = rem & 7;
            int dg = sl ^ (cl & 7);
            float4 v = *reinterpret_cast<const float4*>(
                xT + (((size_t)(b * 8 + dg) * XP + by * 8 + yl) * XP + bx * 16 + cl) * 8);
            *reinterpret_cast<float4*>(xs + idx * 8) = v;
        }
    }
    __syncthreads();   // barrier 1: xs ready (read-only hereafter)

    const int lane = tid & 63;
    const int wid = tid >> 6;
    const int l15 = lane & 15, lh = lane >> 4;

    {   // ---- Phase A: 9-tap implicit GEMM, NO barriers; bf direct from global ----
        const int wr = wid & 1;            // px half (4 image rows)
        const int wc = wid >> 1;           // oc quarter (64 of 256)
        f32x4 acc[4][4];
        const f32x4 zero = {0.f, 0.f, 0.f, 0.f};
        #pragma unroll
        for (int ty = 0; ty < 4; ++ty)
            #pragma unroll
            for (int ot = 0; ot < 4; ++ot) acc[ty][ot] = zero;

        #pragma unroll 3
        for (int tap = 0; tap < 9; ++tap) {
            const int r = tap / 3, s = tap - r * 3;
            const int j = l15 + s;                    // patch col
            #pragma unroll
            for (int h = 0; h < 2; ++h) {
                const int c = h * 4 + lh;             // cin group 0..7
                const int sl = c ^ (j & 7);
                f16x8 af[4], bf[4];
                #pragma unroll
                for (int ot = 0; ot < 4; ++ot) {
                    int oc = wc * 64 + ot * 16 + l15;
                    bf[ot] = *reinterpret_cast<const f16x8*>(
                        wB1 + (size_t)(((tap * 8 + c) * 256 + oc)) * 8);
                }
                #pragma unroll
                for (int ty = 0; ty < 4; ++ty) {
                    int row = wr * 4 + ty + r;
                    af[ty] = *reinterpret_cast<const f16x8*>(xs + (row * 18 + j) * 64 + sl * 8);
                }
                #pragma unroll
                for (int ty = 0; ty < 4; ++ty)
                    #pragma unroll
                    for (int ot = 0; ot < 4; ++ot)
                        acc[ty][ot] = __builtin_amdgcn_mfma_f32_16x16x32_f16(
                            af[ty], bf[ot], acc[ty][ot], 0, 0, 0);
            }
        }

        // ---- Phase A epilogue -> offsb (LDS). D: oc=l15-col, x-offset=lh*4+reg ----
        #pragma unroll
        for (int ot = 0; ot < 4; ++ot) {
            int oc = wc * 64 + ot * 16 + l15;
            if (oc < OCOFFc) {
                float bi = cob[oc];
                bool sig = (oc >= 144);
                int dg, k, comp;
                if (oc < 144) { dg = oc / 18; int rem = oc - dg * 18; k = rem >> 1; comp = rem & 1; }
                else          { int mm = oc - 144; dg = mm / 9; k = mm - dg * 9; comp = 2; }
                int r3 = (dg * 9 + k) * 3 + comp;
                #pragma unroll
                for (int ty = 0; ty < 4; ++ty) {
                    int px = (wr * 4 + ty) * 16 + lh * 4;
                    float v0 = acc[ty][ot][0] + bi, v1 = acc[ty][ot][1] + bi;
                    float v2 = acc[ty][ot][2] + bi, v3 = acc[ty][ot][3] + bi;
                    if (sig) {
                        v0 = 1.f / (1.f + __expf(-v0)); v1 = 1.f / (1.f + __expf(-v1));
                        v2 = 1.f / (1.f + __expf(-v2)); v3 = 1.f / (1.f + __expf(-v3));
                    }
                    __half2* d = reinterpret_cast<__half2*>(&offsb[r3 * 132 + px]);
                    d[0] = __halves2half2(__float2half(v0), __float2half(v1));
                    d[1] = __halves2half2(__float2half(v2), __float2half(v3));
                }
            }
        }
    }
    __syncthreads();   // barrier 2: offsb complete

    // ---- Phase B: wave = image row; dg-pipelined register-staged sampling ----
    const int px = wid * 16 + l15;    // offsb px index
    const int gy = by * 8 + wid;
    const int gx = bx * 16 + l15;

    f32x4 acc2[4];
    const f32x4 zero2 = {0.f, 0.f, 0.f, 0.f};
    #pragma unroll
    for (int n = 0; n < 4; ++n) acc2[n] = zero2;

    float4 gA[12]; float wA[12];
    float4 gB[12]; float wB[12];

    DCN_ISSUE(0, gA, wA);
    #pragma unroll 1
    for (int d = 0; d < 8; d += 2) {
        DCN_ISSUE(d + 1, gB, wB);
        DCN_CONSUME(d, gA, wA);
        if (d + 2 < 8) DCN_ISSUE(d + 2, gA, wA);
        DCN_CONSUME(d + 1, gB, wB);
    }

    // ---- store: D row -> x-offset (lh*4+reg), col -> oc (n*16+l15) ----
    #pragma unroll
    for (int n = 0; n < 4; ++n) {
        int oc = n * 16 + l15;
        float bi = bias[oc];
        float4 v = make_float4(acc2[n][0] + bi, acc2[n][1] + bi,
                               acc2[n][2] + bi, acc2[n][3] + bi);
        *reinterpret_cast<float4*>(
            out + (size_t)(b * 64 + oc) * HWc + gy * 128 + bx * 16 + lh * 4) = v;
    }
}

extern "C" void kernel_launch(void* const* d_in, const int* in_sizes, int n_in,
                              void* d_out, int out_size, void* d_ws, size_t ws_size,
                              hipStream_t stream) {
    const float* x      = (const float*)d_in[0];
    const float* w_off  = (const float*)d_in[1];
    const float* cob    = (const float*)d_in[2];
    const float* weight = (const float*)d_in[3];
    const float* bias   = (const float*)d_in[4];
    float* out = (float*)d_out;
    if (ws_size < WS_NEEDED) return;

    char* ws = (char*)d_ws;
    __half* xT  = (__half*)ws;
    __half* wB1 = (__half*)(ws + WB1_OFF);
    __half* wM  = (__half*)(ws + WM_OFF);

    prep_all<<<1825, 256, 0, stream>>>(x, w_off, weight, xT, wB1, wM);
    dcn_fused_k<<<dim3(8, 16, 2), 512, 0, stream>>>(xT, wB1, cob, wM, bias, out);
}